// Round 1
// baseline (208.861 us; speedup 1.0000x reference)
//
#include <hip/hip_runtime.h>
#include <math.h>

namespace {

typedef __attribute__((ext_vector_type(8))) __fp16 f16x8;
typedef __attribute__((ext_vector_type(4))) float f32x4;

constexpr int IN_DIM = 128;
constexpr int EFF    = 130 * 16;   // W1 node stride (floats)
constexpr int NODES  = 255;
constexpr int TS     = 64;         // samples per block (4 MFMA N-tiles per wave)
constexpr int BLOCK  = 512;        // R16: 8 waves per block
constexpr int NC     = 10;

// ---- prep: W1[:, :128, :] -> MFMA fragment layout, fp16 (single product) ----
// frag element (n, t, lane l, j): W[k = t*32 + (l>>4)*8 + j][hid = l&15]
__global__ __launch_bounds__(256) void prep_w1(const float* __restrict__ W1,
                                               f16x8* __restrict__ wfrag) {
    __shared__ float xs[IN_DIM * 16];      // 8 KB: rows 0..127 of this node
    const int n = blockIdx.x, tid = threadIdx.x;
    const float4* src = (const float4*)(W1 + (size_t)n * EFF);
    ((float4*)xs)[tid]       = src[tid];
    ((float4*)xs)[tid + 256] = src[tid + 256];
    __syncthreads();
    const int l = tid & 63, t = tid >> 6;
    const int k0 = t * 32 + (l >> 4) * 8, hid = l & 15;
    f16x8 hv;
    #pragma unroll
    for (int j = 0; j < 8; ++j)
        hv[j] = (__fp16)xs[(k0 + j) * 16 + hid];   // RNE
    wfrag[(n * 4 + t) * 64 + l] = hv;
}

__device__ __forceinline__ void loadW(const f16x8* __restrict__ wfrag, int n, int l,
                                      f16x8 (&w)[4]) {
    const f16x8* wp = wfrag + (size_t)n * 256 + l;
    #pragma unroll
    for (int t = 0; t < 4; ++t) w[t] = wp[t * 64];
}

__device__ __forceinline__ void mfma16(const f16x8 (&w)[4], const f16x8 (&xh)[4][4],
                                       f32x4 (&acc)[4]) {
    #pragma unroll
    for (int t = 0; t < 4; ++t)
        #pragma unroll
        for (int mt = 0; mt < 4; ++mt)
            acc[mt] = __builtin_amdgcn_mfma_f32_16x16x32_f16(w[t], xh[t][mt], acc[mt], 0, 0, 0);
}

// combine + hid-reduce (3 in-lane adds + 2 shfls per mt) + lane-select
__device__ __forceinline__ float epilogue_score(
    const f32x4 (&acc)[4], const float4& w2q, const float4& wpq, const float4& wgq,
    const float (&par)[4], const float (&gp)[4], float b2v, int quad)
{
    float score01[4];
    #pragma unroll
    for (int mt = 0; mt < 4; ++mt) {
        float ts = 0.0f;
        #pragma unroll
        for (int r = 0; r < 4; ++r) {
            const float wpr = (r == 0) ? wpq.x : (r == 1) ? wpq.y : (r == 2) ? wpq.z : wpq.w;
            const float wgr = (r == 0) ? wgq.x : (r == 1) ? wgq.y : (r == 2) ? wgq.z : wgq.w;
            const float w2r = (r == 0) ? w2q.x : (r == 1) ? w2q.y : (r == 2) ? w2q.z : w2q.w;
            const float h = fmaf(par[mt], wpr, fmaf(gp[mt], wgr, acc[mt][r]));
            ts = fmaf(fmaxf(h, 0.0f), w2r, ts);
        }
        ts += __shfl_xor(ts, 16);
        ts += __shfl_xor(ts, 32);
        score01[mt] = ts;
    }
    const float sa = (quad & 1) ? score01[1] : score01[0];
    const float sb = (quad & 1) ? score01[3] : score01[2];
    return ((quad & 2) ? sb : sa) + b2v;
}

// ---- main fused tree kernel ----
// R16: occupancy doubling. Grid is fixed at 512 blocks (= 2 blocks/CU), so
// shrinking LDS cannot add resident waves; instead widen the block to 8 waves
// (BLOCK=512) and split nodes 8 ways. 2 blocks/CU x 8 waves = 4 waves/SIMD
// (was 2), and the per-wave serial path halves (~31 node-iters, was ~64).
// Subtree ownership re-derived for 8 waves: pp slots [16w,16w+16) and
// par/gp score reads are wave-local for d>=3; d=3's parent (d=2 scores) is
// cross-wave, so barriers after d=0,1,2 (3 total, was 2). Per-depth scbuf
// regions (offset 2^d-1) unchanged -> no WAR under wave drift. R14/R15
// software pipeline and all arithmetic unchanged.
__global__ __launch_bounds__(BLOCK) __attribute__((amdgpu_waves_per_eu(4)))
void tree_mfma(
    const float* __restrict__ x, const float* __restrict__ path_prob,
    const float* __restrict__ W1, const float* __restrict__ b1,
    const float* __restrict__ w2, const float* __restrict__ b2,
    const float* __restrict__ leaf_logits,
    const f16x8* __restrict__ wfrag,
    float* __restrict__ out)
{
    __shared__ float pp[128][TS];          // 32 KB: path probs, depths 0..6 only
    __shared__ float scbuf[127][TS];       // 31.75 KB: depth-d scores at row (2^d - 1)

    const int tid  = threadIdx.x;
    const int wv   = tid >> 6, l = tid & 63;
    const int quad = l >> 4,   col = l & 15;
    const int s0   = blockIdx.x * TS;

    if (tid < TS) pp[0][tid] = path_prob[s0 + tid];

    // x fragments (fp16): B operand B[k = t*32+quad*8+j][col]
    f16x8 xh[4][4];
    #pragma unroll
    for (int t = 0; t < 4; ++t)
        #pragma unroll
        for (int mt = 0; mt < 4; ++mt) {
            const float* xp = x + (size_t)(s0 + mt * 16 + col) * IN_DIM + t * 32 + quad * 8;
            float4 v0 = ((const float4*)xp)[0];
            float4 v1 = ((const float4*)xp)[1];
            float vv[8] = {v0.x, v0.y, v0.z, v0.w, v1.x, v1.y, v1.z, v1.w};
            f16x8 hv;
            #pragma unroll
            for (int j = 0; j < 8; ++j) hv[j] = (__fp16)vv[j];
            xh[t][mt] = hv;
        }

    // ---------------- depths 0..6: software-pipelined, subtree-owned ----------------
    for (int d = 0; d < 7; ++d) {
        const int nd = 1 << d;
        float (*scW)[TS]  = (float(*)[TS])&scbuf[nd - 1][0];
        float (*scP)[TS]  = (float(*)[TS])&scbuf[(nd >> 1) - 1][0];   // d-1 region (d>=1)
        float (*scP2)[TS] = (float(*)[TS])&scbuf[(nd >> 2) - 1][0];   // d-2 region (d>=2)
        const int stride = 128 >> d, half = 64 >> d;

        int nlo, nhi;
        if (d >= 3) { nlo = wv * (nd >> 3); nhi = nlo + (nd >> 3); }
        else        { nlo = wv; nhi = (wv < nd) ? wv + 1 : wv; }      // d<3: waves 0..nd-1

        bool havePrev = false;
        f32x4 accP[4];
        float4 p_w2q, p_wpq, p_wgq;
        float  p_b2v = 0.f, p_ppar = 0.f;
        float  p_par[4], p_gp[4];
        int    p_slot = 0, p_nl = 0;

        for (int nl = nlo; nl < nhi; ++nl) {
            const int n = nd - 1 + nl;

            // (1) issue this node's W + b1 loads (hidden under prev epilogue)
            f16x8 w[4];
            loadW(wfrag, n, l, w);
            const float4 b1q = ((const float4*)(b1 + n * 16))[quad];

            // (2) overlapped epilogue of previous node
            if (havePrev) {
                const float sv = epilogue_score(accP, p_w2q, p_wpq, p_wgq, p_par, p_gp, p_b2v, quad);
                scW[p_nl][l] = sv;
                const float p = 1.0f / (1.0f + __expf(-sv));
                pp[p_slot][l]        = p_ppar * p;
                pp[p_slot + half][l] = p_ppar * (1.0f - p);
            }

            // (3) this node's epilogue scalars (consumed NEXT iteration)
            const float4 w2q = ((const float4*)(w2 + n * 16))[quad];
            const float4 wpq = ((const float4*)(W1 + (size_t)n * EFF + 128 * 16))[quad];
            const float4 wgq = ((const float4*)(W1 + (size_t)n * EFF + 129 * 16))[quad];
            const float  b2v = b2[n];
            const int    slot = nl * stride;
            const float  ppar = pp[slot][l];
            float par[4], gp[4];
            #pragma unroll
            for (int mt = 0; mt < 4; ++mt) {
                const int scol = mt * 16 + col;
                par[mt] = (d >= 1) ? scP[nl >> 1][scol] : 0.0f;
                gp[mt]  = (d >= 2) ? scP2[nl >> 2][scol] : 0.0f;
            }

            // (4) MFMA into fresh accumulator (bias folded into init)
            f32x4 binit = {b1q.x, b1q.y, b1q.z, b1q.w};
            f32x4 acc[4] = {binit, binit, binit, binit};
            mfma16(w, xh, acc);

            // (5) carry state
            #pragma unroll
            for (int mt = 0; mt < 4; ++mt) accP[mt] = acc[mt];
            p_w2q = w2q; p_wpq = wpq; p_wgq = wgq;
            p_b2v = b2v; p_ppar = ppar;
            #pragma unroll
            for (int mt = 0; mt < 4; ++mt) { p_par[mt] = par[mt]; p_gp[mt] = gp[mt]; }
            p_slot = slot; p_nl = nl;
            havePrev = true;
        }
        // drain
        if (havePrev) {
            const float sv = epilogue_score(accP, p_w2q, p_wpq, p_wgq, p_par, p_gp, p_b2v, quad);
            scW[p_nl][l] = sv;
            const float p = 1.0f / (1.0f + __expf(-sv));
            pp[p_slot][l]        = p_ppar * p;
            pp[p_slot + half][l] = p_ppar * (1.0f - p);
        }
        // d0/d1/d2 results are read cross-wave (d>=4 reads are wave-local,
        // d=3's cross-wave inputs are covered by the d=2 barrier)
        if (d < 3) __syncthreads();
    }

    // ---------------- depth 7: pipelined fold of leaf mixture (wave-local) ----------------
    float oacc[NC];
    #pragma unroll
    for (int c = 0; c < NC; ++c) oacc[c] = 0.0f;
    {
        float (*scP)[TS]  = (float(*)[TS])&scbuf[63][0];   // d=6 scores
        float (*scP2)[TS] = (float(*)[TS])&scbuf[31][0];   // d=5 scores

        bool havePrev = false;
        f32x4 accP[4];
        float4 p_w2q, p_wpq, p_wgq;
        float  p_b2v = 0.f, p_ppar = 0.f;
        float  p_par[4], p_gp[4];
        int    p_nl = 0;

        const int nlo = wv * 16, nhi = nlo + 16;
        for (int nl = nlo; nl < nhi; ++nl) {
            const int n = 127 + nl;

            f16x8 w[4];
            loadW(wfrag, n, l, w);
            const float4 b1q = ((const float4*)(b1 + n * 16))[quad];

            if (havePrev) {
                const float sv = epilogue_score(accP, p_w2q, p_wpq, p_wgq, p_par, p_gp, p_b2v, quad);
                const float p = 1.0f / (1.0f + __expf(-sv));
                const float pL = p_ppar * p;
                const float pR = p_ppar * (1.0f - p);
                const float* llp = leaf_logits + (size_t)(2 * p_nl) * NC;
                #pragma unroll
                for (int c = 0; c < NC; ++c)
                    oacc[c] = fmaf(pL, llp[c], fmaf(pR, llp[NC + c], oacc[c]));
            }

            const float4 w2q = ((const float4*)(w2 + n * 16))[quad];
            const float4 wpq = ((const float4*)(W1 + (size_t)n * EFF + 128 * 16))[quad];
            const float4 wgq = ((const float4*)(W1 + (size_t)n * EFF + 129 * 16))[quad];
            const float  b2v = b2[n];
            const float  ppar = pp[nl][l];
            float par[4], gp[4];
            #pragma unroll
            for (int mt = 0; mt < 4; ++mt) {
                const int scol = mt * 16 + col;
                par[mt] = scP[nl >> 1][scol];
                gp[mt]  = scP2[nl >> 2][scol];
            }

            f32x4 binit = {b1q.x, b1q.y, b1q.z, b1q.w};
            f32x4 acc[4] = {binit, binit, binit, binit};
            mfma16(w, xh, acc);

            #pragma unroll
            for (int mt = 0; mt < 4; ++mt) accP[mt] = acc[mt];
            p_w2q = w2q; p_wpq = wpq; p_wgq = wgq;
            p_b2v = b2v; p_ppar = ppar;
            #pragma unroll
            for (int mt = 0; mt < 4; ++mt) { p_par[mt] = par[mt]; p_gp[mt] = gp[mt]; }
            p_nl = nl;
            havePrev = true;
        }
        // drain
        if (havePrev) {
            const float sv = epilogue_score(accP, p_w2q, p_wpq, p_wgq, p_par, p_gp, p_b2v, quad);
            const float p = 1.0f / (1.0f + __expf(-sv));
            const float pL = p_ppar * p;
            const float pR = p_ppar * (1.0f - p);
            const float* llp = leaf_logits + (size_t)(2 * p_nl) * NC;
            #pragma unroll
            for (int c = 0; c < NC; ++c)
                oacc[c] = fmaf(pL, llp[c], fmaf(pR, llp[NC + c], oacc[c]));
        }
    }

    // ---------------- cross-wave out reduction through scbuf ----------------
    __syncthreads();
    {
        float* red = &scbuf[0][0];         // 8*64*10 = 5120 floats <= 8128
        #pragma unroll
        for (int c = 0; c < NC; ++c)
            red[(wv * 64 + l) * NC + c] = oacc[c];
    }
    __syncthreads();
    {
        const float* red = &scbuf[0][0];
        for (int i = tid; i < TS * NC; i += BLOCK) {
            float v = red[i]        + red[640 + i]  + red[1280 + i] + red[1920 + i]
                    + red[2560 + i] + red[3200 + i] + red[3840 + i] + red[4480 + i];
            out[(size_t)s0 * NC + i] = v;
        }
    }
}

} // namespace

extern "C" void kernel_launch(void* const* d_in, const int* in_sizes, int n_in,
                              void* d_out, int out_size, void* d_ws, size_t ws_size,
                              hipStream_t stream) {
    const float* x           = (const float*)d_in[0];
    const float* path_prob   = (const float*)d_in[1];
    const float* W1          = (const float*)d_in[2];
    const float* b1          = (const float*)d_in[3];
    const float* w2          = (const float*)d_in[4];
    const float* b2          = (const float*)d_in[5];
    const float* leaf_logits = (const float*)d_in[6];
    float* out = (float*)d_out;

    const int batch = in_sizes[0] / IN_DIM;                // 32768
    f16x8* wfrag = (f16x8*)d_ws;                           // 255*4*64*16B ~= 1.04 MB

    hipLaunchKernelGGL(prep_w1, dim3(NODES), dim3(256), 0, stream, W1, wfrag);
    hipLaunchKernelGGL(tree_mfma, dim3(batch / TS), dim3(BLOCK), 0, stream,
                       x, path_prob, W1, b1, w2, b2, leaf_logits, wfrag, out);
}

// Round 2
// 149.213 us; speedup vs baseline: 1.3998x; 1.3998x over previous
//
#include <hip/hip_runtime.h>
#include <math.h>

namespace {

typedef __attribute__((ext_vector_type(8))) __fp16 f16x8;
typedef __attribute__((ext_vector_type(4))) float f32x4;

constexpr int IN_DIM = 128;
constexpr int EFF    = 130 * 16;   // W1 node stride (floats)
constexpr int NODES  = 255;
constexpr int TS     = 64;         // samples per block (4 MFMA N-tiles per wave)
constexpr int BLOCK  = 512;        // 8 waves per block
constexpr int NC     = 10;

// ---- prep: W1[:, :128, :] -> MFMA fragment layout, fp16 (single product) ----
// frag element (n, t, lane l, j): W[k = t*32 + (l>>4)*8 + j][hid = l&15]
__global__ __launch_bounds__(256) void prep_w1(const float* __restrict__ W1,
                                               f16x8* __restrict__ wfrag) {
    __shared__ float xs[IN_DIM * 16];      // 8 KB: rows 0..127 of this node
    const int n = blockIdx.x, tid = threadIdx.x;
    const float4* src = (const float4*)(W1 + (size_t)n * EFF);
    ((float4*)xs)[tid]       = src[tid];
    ((float4*)xs)[tid + 256] = src[tid + 256];
    __syncthreads();
    const int l = tid & 63, t = tid >> 6;
    const int k0 = t * 32 + (l >> 4) * 8, hid = l & 15;
    f16x8 hv;
    #pragma unroll
    for (int j = 0; j < 8; ++j)
        hv[j] = (__fp16)xs[(k0 + j) * 16 + hid];   // RNE
    wfrag[(n * 4 + t) * 64 + l] = hv;
}

__device__ __forceinline__ void loadW(const f16x8* __restrict__ wfrag, int n, int l,
                                      f16x8 (&w)[4]) {
    const f16x8* wp = wfrag + (size_t)n * 256 + l;
    #pragma unroll
    for (int t = 0; t < 4; ++t) w[t] = wp[t * 64];
}

__device__ __forceinline__ void mfma16(const f16x8 (&w)[4], const f16x8 (&xh)[4][4],
                                       f32x4 (&acc)[4]) {
    #pragma unroll
    for (int t = 0; t < 4; ++t)
        #pragma unroll
        for (int mt = 0; mt < 4; ++mt)
            acc[mt] = __builtin_amdgcn_mfma_f32_16x16x32_f16(w[t], xh[t][mt], acc[mt], 0, 0, 0);
}

// combine + hid-reduce (3 in-lane adds + 2 shfls per mt) + lane-select
__device__ __forceinline__ float epilogue_score(
    const f32x4 (&acc)[4], const float4& w2q, const float4& wpq, const float4& wgq,
    const float (&par)[4], const float (&gp)[4], float b2v, int quad)
{
    float score01[4];
    #pragma unroll
    for (int mt = 0; mt < 4; ++mt) {
        float ts = 0.0f;
        #pragma unroll
        for (int r = 0; r < 4; ++r) {
            const float wpr = (r == 0) ? wpq.x : (r == 1) ? wpq.y : (r == 2) ? wpq.z : wpq.w;
            const float wgr = (r == 0) ? wgq.x : (r == 1) ? wgq.y : (r == 2) ? wgq.z : wgq.w;
            const float w2r = (r == 0) ? w2q.x : (r == 1) ? w2q.y : (r == 2) ? w2q.z : w2q.w;
            const float h = fmaf(par[mt], wpr, fmaf(gp[mt], wgr, acc[mt][r]));
            ts = fmaf(fmaxf(h, 0.0f), w2r, ts);
        }
        ts += __shfl_xor(ts, 16);
        ts += __shfl_xor(ts, 32);
        score01[mt] = ts;
    }
    const float sa = (quad & 1) ? score01[1] : score01[0];
    const float sb = (quad & 1) ? score01[3] : score01[2];
    return ((quad & 2) ? sb : sa) + b2v;
}

// ---- main fused tree kernel ----
// R17: R16's 8-wave block, but with the VGPR budget fixed. R16's
// amdgpu_waves_per_eu(4) forced a 64-VGPR cap -> massive scratch spills
// (WRITE_SIZE 1.3->41.8 MB, FETCH 12.7->79 MB, dur 149us). Residency is
// LDS-limited anyway: 63.75 KB/block -> 2 blocks/CU x 8 waves = 4 waves/SIMD,
// which only needs VGPR <= 128 (m69: waves halve at 64/128/256). So cap at
// 128 via waves_per_eu(2): no spills (R15 fit the same state in 88), same
// 2x occupancy vs R15, half the per-wave serial node count.
// Subtree ownership for 8 waves: pp slots [16w,16w+16) and par/gp reads are
// wave-local for d>=4; d=3's parent (d=2 scores) is cross-wave -> barriers
// after d=0,1,2 (3 total). Software pipeline and arithmetic unchanged.
__global__ __launch_bounds__(BLOCK) __attribute__((amdgpu_waves_per_eu(2)))
void tree_mfma(
    const float* __restrict__ x, const float* __restrict__ path_prob,
    const float* __restrict__ W1, const float* __restrict__ b1,
    const float* __restrict__ w2, const float* __restrict__ b2,
    const float* __restrict__ leaf_logits,
    const f16x8* __restrict__ wfrag,
    float* __restrict__ out)
{
    __shared__ float pp[128][TS];          // 32 KB: path probs, depths 0..6 only
    __shared__ float scbuf[127][TS];       // 31.75 KB: depth-d scores at row (2^d - 1)

    const int tid  = threadIdx.x;
    const int wv   = tid >> 6, l = tid & 63;
    const int quad = l >> 4,   col = l & 15;
    const int s0   = blockIdx.x * TS;

    if (tid < TS) pp[0][tid] = path_prob[s0 + tid];

    // x fragments (fp16): B operand B[k = t*32+quad*8+j][col]
    f16x8 xh[4][4];
    #pragma unroll
    for (int t = 0; t < 4; ++t)
        #pragma unroll
        for (int mt = 0; mt < 4; ++mt) {
            const float* xp = x + (size_t)(s0 + mt * 16 + col) * IN_DIM + t * 32 + quad * 8;
            float4 v0 = ((const float4*)xp)[0];
            float4 v1 = ((const float4*)xp)[1];
            float vv[8] = {v0.x, v0.y, v0.z, v0.w, v1.x, v1.y, v1.z, v1.w};
            f16x8 hv;
            #pragma unroll
            for (int j = 0; j < 8; ++j) hv[j] = (__fp16)vv[j];
            xh[t][mt] = hv;
        }

    // ---------------- depths 0..6: software-pipelined, subtree-owned ----------------
    for (int d = 0; d < 7; ++d) {
        const int nd = 1 << d;
        float (*scW)[TS]  = (float(*)[TS])&scbuf[nd - 1][0];
        float (*scP)[TS]  = (float(*)[TS])&scbuf[(nd >> 1) - 1][0];   // d-1 region (d>=1)
        float (*scP2)[TS] = (float(*)[TS])&scbuf[(nd >> 2) - 1][0];   // d-2 region (d>=2)
        const int stride = 128 >> d, half = 64 >> d;

        int nlo, nhi;
        if (d >= 3) { nlo = wv * (nd >> 3); nhi = nlo + (nd >> 3); }
        else        { nlo = wv; nhi = (wv < nd) ? wv + 1 : wv; }      // d<3: waves 0..nd-1

        bool havePrev = false;
        f32x4 accP[4];
        float4 p_w2q, p_wpq, p_wgq;
        float  p_b2v = 0.f, p_ppar = 0.f;
        float  p_par[4], p_gp[4];
        int    p_slot = 0, p_nl = 0;

        for (int nl = nlo; nl < nhi; ++nl) {
            const int n = nd - 1 + nl;

            // (1) issue this node's W + b1 loads (hidden under prev epilogue)
            f16x8 w[4];
            loadW(wfrag, n, l, w);
            const float4 b1q = ((const float4*)(b1 + n * 16))[quad];

            // (2) overlapped epilogue of previous node
            if (havePrev) {
                const float sv = epilogue_score(accP, p_w2q, p_wpq, p_wgq, p_par, p_gp, p_b2v, quad);
                scW[p_nl][l] = sv;
                const float p = 1.0f / (1.0f + __expf(-sv));
                pp[p_slot][l]        = p_ppar * p;
                pp[p_slot + half][l] = p_ppar * (1.0f - p);
            }

            // (3) this node's epilogue scalars (consumed NEXT iteration)
            const float4 w2q = ((const float4*)(w2 + n * 16))[quad];
            const float4 wpq = ((const float4*)(W1 + (size_t)n * EFF + 128 * 16))[quad];
            const float4 wgq = ((const float4*)(W1 + (size_t)n * EFF + 129 * 16))[quad];
            const float  b2v = b2[n];
            const int    slot = nl * stride;
            const float  ppar = pp[slot][l];
            float par[4], gp[4];
            #pragma unroll
            for (int mt = 0; mt < 4; ++mt) {
                const int scol = mt * 16 + col;
                par[mt] = (d >= 1) ? scP[nl >> 1][scol] : 0.0f;
                gp[mt]  = (d >= 2) ? scP2[nl >> 2][scol] : 0.0f;
            }

            // (4) MFMA into fresh accumulator (bias folded into init)
            f32x4 binit = {b1q.x, b1q.y, b1q.z, b1q.w};
            f32x4 acc[4] = {binit, binit, binit, binit};
            mfma16(w, xh, acc);

            // (5) carry state
            #pragma unroll
            for (int mt = 0; mt < 4; ++mt) accP[mt] = acc[mt];
            p_w2q = w2q; p_wpq = wpq; p_wgq = wgq;
            p_b2v = b2v; p_ppar = ppar;
            #pragma unroll
            for (int mt = 0; mt < 4; ++mt) { p_par[mt] = par[mt]; p_gp[mt] = gp[mt]; }
            p_slot = slot; p_nl = nl;
            havePrev = true;
        }
        // drain
        if (havePrev) {
            const float sv = epilogue_score(accP, p_w2q, p_wpq, p_wgq, p_par, p_gp, p_b2v, quad);
            scW[p_nl][l] = sv;
            const float p = 1.0f / (1.0f + __expf(-sv));
            pp[p_slot][l]        = p_ppar * p;
            pp[p_slot + half][l] = p_ppar * (1.0f - p);
        }
        // d0/d1/d2 results are read cross-wave (d>=4 reads are wave-local,
        // d=3's cross-wave inputs are covered by the d=2 barrier)
        if (d < 3) __syncthreads();
    }

    // ---------------- depth 7: pipelined fold of leaf mixture (wave-local) ----------------
    float oacc[NC];
    #pragma unroll
    for (int c = 0; c < NC; ++c) oacc[c] = 0.0f;
    {
        float (*scP)[TS]  = (float(*)[TS])&scbuf[63][0];   // d=6 scores
        float (*scP2)[TS] = (float(*)[TS])&scbuf[31][0];   // d=5 scores

        bool havePrev = false;
        f32x4 accP[4];
        float4 p_w2q, p_wpq, p_wgq;
        float  p_b2v = 0.f, p_ppar = 0.f;
        float  p_par[4], p_gp[4];
        int    p_nl = 0;

        const int nlo = wv * 16, nhi = nlo + 16;
        for (int nl = nlo; nl < nhi; ++nl) {
            const int n = 127 + nl;

            f16x8 w[4];
            loadW(wfrag, n, l, w);
            const float4 b1q = ((const float4*)(b1 + n * 16))[quad];

            if (havePrev) {
                const float sv = epilogue_score(accP, p_w2q, p_wpq, p_wgq, p_par, p_gp, p_b2v, quad);
                const float p = 1.0f / (1.0f + __expf(-sv));
                const float pL = p_ppar * p;
                const float pR = p_ppar * (1.0f - p);
                const float* llp = leaf_logits + (size_t)(2 * p_nl) * NC;
                #pragma unroll
                for (int c = 0; c < NC; ++c)
                    oacc[c] = fmaf(pL, llp[c], fmaf(pR, llp[NC + c], oacc[c]));
            }

            const float4 w2q = ((const float4*)(w2 + n * 16))[quad];
            const float4 wpq = ((const float4*)(W1 + (size_t)n * EFF + 128 * 16))[quad];
            const float4 wgq = ((const float4*)(W1 + (size_t)n * EFF + 129 * 16))[quad];
            const float  b2v = b2[n];
            const float  ppar = pp[nl][l];
            float par[4], gp[4];
            #pragma unroll
            for (int mt = 0; mt < 4; ++mt) {
                const int scol = mt * 16 + col;
                par[mt] = scP[nl >> 1][scol];
                gp[mt]  = scP2[nl >> 2][scol];
            }

            f32x4 binit = {b1q.x, b1q.y, b1q.z, b1q.w};
            f32x4 acc[4] = {binit, binit, binit, binit};
            mfma16(w, xh, acc);

            #pragma unroll
            for (int mt = 0; mt < 4; ++mt) accP[mt] = acc[mt];
            p_w2q = w2q; p_wpq = wpq; p_wgq = wgq;
            p_b2v = b2v; p_ppar = ppar;
            #pragma unroll
            for (int mt = 0; mt < 4; ++mt) { p_par[mt] = par[mt]; p_gp[mt] = gp[mt]; }
            p_nl = nl;
            havePrev = true;
        }
        // drain
        if (havePrev) {
            const float sv = epilogue_score(accP, p_w2q, p_wpq, p_wgq, p_par, p_gp, p_b2v, quad);
            const float p = 1.0f / (1.0f + __expf(-sv));
            const float pL = p_ppar * p;
            const float pR = p_ppar * (1.0f - p);
            const float* llp = leaf_logits + (size_t)(2 * p_nl) * NC;
            #pragma unroll
            for (int c = 0; c < NC; ++c)
                oacc[c] = fmaf(pL, llp[c], fmaf(pR, llp[NC + c], oacc[c]));
        }
    }

    // ---------------- cross-wave out reduction through scbuf ----------------
    __syncthreads();
    {
        float* red = &scbuf[0][0];         // 8*64*10 = 5120 floats <= 8128
        #pragma unroll
        for (int c = 0; c < NC; ++c)
            red[(wv * 64 + l) * NC + c] = oacc[c];
    }
    __syncthreads();
    {
        const float* red = &scbuf[0][0];
        for (int i = tid; i < TS * NC; i += BLOCK) {
            float v = red[i]        + red[640 + i]  + red[1280 + i] + red[1920 + i]
                    + red[2560 + i] + red[3200 + i] + red[3840 + i] + red[4480 + i];
            out[(size_t)s0 * NC + i] = v;
        }
    }
}

} // namespace

extern "C" void kernel_launch(void* const* d_in, const int* in_sizes, int n_in,
                              void* d_out, int out_size, void* d_ws, size_t ws_size,
                              hipStream_t stream) {
    const float* x           = (const float*)d_in[0];
    const float* path_prob   = (const float*)d_in[1];
    const float* W1          = (const float*)d_in[2];
    const float* b1          = (const float*)d_in[3];
    const float* w2          = (const float*)d_in[4];
    const float* b2          = (const float*)d_in[5];
    const float* leaf_logits = (const float*)d_in[6];
    float* out = (float*)d_out;

    const int batch = in_sizes[0] / IN_DIM;                // 32768
    f16x8* wfrag = (f16x8*)d_ws;                           // 255*4*64*16B ~= 1.04 MB

    hipLaunchKernelGGL(prep_w1, dim3(NODES), dim3(256), 0, stream, W1, wfrag);
    hipLaunchKernelGGL(tree_mfma, dim3(batch / TS), dim3(BLOCK), 0, stream,
                       x, path_prob, W1, b1, w2, b2, leaf_logits, wfrag, out);
}